// Round 13
// baseline (26.367 us; speedup 1.0000x reference)
//
#include <hip/hip_runtime.h>

#define KDIM 1024
#define DDIM 128
#define TS   32
#define LDP  132   // padded LDS row stride (floats)

// ---------------------------------------------------------------------------
// Kernel 1: U = span @ (W1a + W1c) + b1 ; V = ant @ (W1b - W1c)
// 256 blocks x 256 threads; 8 rows of one matrix per block.
// ---------------------------------------------------------------------------
__global__ __launch_bounds__(256) void prep_uv(
    const float* __restrict__ span, const float* __restrict__ ant,
    const float* __restrict__ W1,   const float* __restrict__ b1,
    float* __restrict__ U, float* __restrict__ V)
{
    __shared__ float a_lds[8 * DDIM];    // 4 KB

    const int tid  = threadIdx.x;
    const int mat  = blockIdx.x & 1;     // 0 -> U (span), 1 -> V (ant)
    const int rblk = blockIdx.x >> 1;    // 0..127, 8 rows each
    const float* __restrict__ A = mat ? ant : span;
    float* __restrict__ outp    = mat ? V : U;

    ((float4*)a_lds)[tid] = ((const float4*)(A + rblk * 8 * DDIM))[tid];
    __syncthreads();

    const int c  = tid & 127;
    const int rg = tid >> 7;             // 0/1 -> rows rg*4..rg*4+3
    const float binit = mat ? 0.0f : b1[c];
    float acc0 = binit, acc1 = binit, acc2 = binit, acc3 = binit;

    const float* __restrict__ Wx = W1 + (mat ? DDIM * DDIM : 0);
    const float* __restrict__ Wc = W1 + 2 * DDIM * DDIM;
    const float sgn = mat ? -1.0f : 1.0f;

#pragma unroll 4
    for (int d0 = 0; d0 < DDIM; d0 += 4) {
        float w0 = Wx[(d0 + 0) * DDIM + c] + sgn * Wc[(d0 + 0) * DDIM + c];
        float w1 = Wx[(d0 + 1) * DDIM + c] + sgn * Wc[(d0 + 1) * DDIM + c];
        float w2 = Wx[(d0 + 2) * DDIM + c] + sgn * Wc[(d0 + 2) * DDIM + c];
        float w3 = Wx[(d0 + 3) * DDIM + c] + sgn * Wc[(d0 + 3) * DDIM + c];
        float4 a0 = *(const float4*)&a_lds[(rg * 4 + 0) * DDIM + d0];
        float4 a1 = *(const float4*)&a_lds[(rg * 4 + 1) * DDIM + d0];
        float4 a2 = *(const float4*)&a_lds[(rg * 4 + 2) * DDIM + d0];
        float4 a3 = *(const float4*)&a_lds[(rg * 4 + 3) * DDIM + d0];
        acc0 += a0.x * w0 + a0.y * w1 + a0.z * w2 + a0.w * w3;
        acc1 += a1.x * w0 + a1.y * w1 + a1.z * w2 + a1.w * w3;
        acc2 += a2.x * w0 + a2.y * w1 + a2.z * w2 + a2.w * w3;
        acc3 += a3.x * w0 + a3.y * w1 + a3.z * w2 + a3.w * w3;
    }
    const int rbase = rblk * 8 + rg * 4;
    outp[(rbase + 0) * DDIM + c] = acc0;
    outp[(rbase + 1) * DDIM + c] = acc1;
    outp[(rbase + 2) * DDIM + c] = acc2;
    outp[(rbase + 3) * DDIM + c] = acc3;
}

// ---------------------------------------------------------------------------
// Kernel 2: out[i][j] = (i>j) ? b2 + sum_c relu(U[i][c]+V[j][c])*W2[c] : 0
// grid (32,32) of 32x32 tiles, 256 threads, 2x2 micro-tile per thread.
// (R0-measured best: 24.2 us. 4 waves/block -> latency hiding; ~34 KB LDS
// -> 4 blocks/CU; nominal V-read bank aliasing measured irrelevant.)
// ---------------------------------------------------------------------------
__global__ __launch_bounds__(256) void pair_score(
    const float* __restrict__ U, const float* __restrict__ V,
    const float* __restrict__ W2, const float* __restrict__ b2,
    float* __restrict__ out)
{
    const int bj  = blockIdx.x;   // column tile
    const int bi  = blockIdx.y;   // row tile
    const int tid = threadIdx.x;

    if (bi < bj) {
        // strictly-upper tile: zero-fill exactly this 32x32 tile (256 float4).
        const int r  = tid >> 3;          // 0..31
        const int c4 = (tid & 7) << 2;    // 0,4,...,28
        *(float4*)&out[(bi * TS + r) * KDIM + bj * TS + c4] =
            make_float4(0.f, 0.f, 0.f, 0.f);
        return;
    }

    __shared__ float Ul[TS * LDP];
    __shared__ float Vl[TS * LDP];
    __shared__ float W2l[DDIM];

    {   // stage U/V tiles (32 rows x 128 floats = 1024 float4 each)
        const float4* us = (const float4*)(U + bi * TS * DDIM);
        const float4* vs = (const float4*)(V + bj * TS * DDIM);
#pragma unroll
        for (int k = 0; k < 4; ++k) {
            int idx = tid + k * 256;      // 0..1023
            int r   = idx >> 5;           // row (32 float4 per row)
            int c4  = idx & 31;           // float4 index within row
            *(float4*)&Ul[r * LDP + c4 * 4] = us[idx];
            *(float4*)&Vl[r * LDP + c4 * 4] = vs[idx];
        }
        if (tid < 32) *(float4*)&W2l[tid * 4] = *(const float4*)&W2[tid * 4];
    }
    __syncthreads();

    const int tj = tid & 15;
    const int ti = tid >> 4;
    const int i0 = ti * 2;
    const int j0 = tj * 2;
    const float b2v = b2[0];
    float a00 = b2v, a01 = b2v, a10 = b2v, a11 = b2v;

#pragma unroll
    for (int d = 0; d < DDIM; d += 4) {
        float4 u0 = *(const float4*)&Ul[i0 * LDP + d];
        float4 u1 = *(const float4*)&Ul[(i0 + 1) * LDP + d];
        float4 v0 = *(const float4*)&Vl[j0 * LDP + d];
        float4 v1 = *(const float4*)&Vl[(j0 + 1) * LDP + d];
        float4 w  = *(const float4*)&W2l[d];
#define STEP(C)                                   \
        a00 += fmaxf(u0.C + v0.C, 0.f) * w.C;     \
        a01 += fmaxf(u0.C + v1.C, 0.f) * w.C;     \
        a10 += fmaxf(u1.C + v0.C, 0.f) * w.C;     \
        a11 += fmaxf(u1.C + v1.C, 0.f) * w.C;
        STEP(x) STEP(y) STEP(z) STEP(w)
#undef STEP
    }

    const int gi0 = bi * TS + i0;
    const int gj0 = bj * TS + j0;
    float2 r0, r1;
    r0.x = (gi0     > gj0    ) ? a00 : 0.f;
    r0.y = (gi0     > gj0 + 1) ? a01 : 0.f;
    r1.x = (gi0 + 1 > gj0    ) ? a10 : 0.f;
    r1.y = (gi0 + 1 > gj0 + 1) ? a11 : 0.f;
    *(float2*)&out[ gi0      * KDIM + gj0] = r0;
    *(float2*)&out[(gi0 + 1) * KDIM + gj0] = r1;
}

// ---------------------------------------------------------------------------
extern "C" void kernel_launch(void* const* d_in, const int* in_sizes, int n_in,
                              void* d_out, int out_size, void* d_ws, size_t ws_size,
                              hipStream_t stream)
{
    const float* span = (const float*)d_in[0];
    const float* ant  = (const float*)d_in[1];
    const float* W1   = (const float*)d_in[2];
    const float* b1   = (const float*)d_in[3];
    const float* W2   = (const float*)d_in[4];
    const float* b2   = (const float*)d_in[5];
    float* out = (float*)d_out;

    float* U = (float*)d_ws;                 // 1024*128 floats (512 KB)
    float* V = U + KDIM * DDIM;              // next 512 KB (1 MB ws total)

    prep_uv<<<dim3(256), 256, 0, stream>>>(span, ant, W1, b1, U, V);
    pair_score<<<dim3(32, 32), 256, 0, stream>>>(U, V, W2, b2, out);
}